// Round 11
// baseline (304.253 us; speedup 1.0000x reference)
//
#include <hip/hip_runtime.h>

#define HW 1024
#define TWO_PI_F 6.28318530717958647692f
#define NSLOT 64   // atomic spreading: 64 slots per accumulator, 5 accumulators

__device__ __forceinline__ float2 cmulf(float2 a, float2 b){
  return make_float2(a.x*b.x - a.y*b.y, a.x*b.y + a.y*b.x);
}

// fast atan2: octant reduction + 9th-order odd minimax poly, max err ~1e-4 rad.
__device__ __forceinline__ float fast_atan2f(float y, float x){
  float ax = fabsf(x), ay = fabsf(y);
  float mx = fmaxf(ax, ay), mn = fminf(ax, ay);
  float a  = mn * __builtin_amdgcn_rcpf(fmaxf(mx, 1e-37f));
  float s  = a * a;
  float r  = ((((0.0208351f*s - 0.085133f)*s + 0.180141f)*s - 0.3302995f)*s
              + 0.999866f) * a;
  r = (ay > ax) ? 1.57079632679f - r : r;
  r = (x < 0.f) ? 3.14159265359f - r : r;
  return (y < 0.f) ? -r : r;
}

// 256-thread block reduction (4 waves of 64), float
__device__ __forceinline__ float block_reduce_add_f(float v, float* sc){
  int tid = threadIdx.x;
  #pragma unroll
  for (int o = 32; o > 0; o >>= 1) v += __shfl_down(v, o, 64);
  __syncthreads();
  if ((tid & 63) == 0) sc[tid >> 6] = v;
  __syncthreads();
  return sc[0] + sc[1] + sc[2] + sc[3];
}

// merged setup: zero accumulators + twiddle table (one launch)
__global__ void setup_kernel(double* acc, float2* twg){
  int i = threadIdx.x + blockIdx.x * 256;   // grid 2 x 256 -> 0..511
  if (i < 5 * NSLOT) acc[i] = 0.0;
  if (i < 512){
    float s, c; sincosf(-TWO_PI_F * (float)i * (1.f/1024.f), &s, &c);
    twg[i] = make_float2(c, s);
  }
}

// ---------------------------------------------------------------------------
// Wave-level 1024-pt FFT (verified R6-R10): 64 (shfl_xor) x 16 (in-register).
// Input: lane q, slot j holds x[j + 16*brev6(q)]. Output: slot j = X[q + 64*j].
// ---------------------------------------------------------------------------
#define FC 0.70710678118654752f
#define FC1 0.92387953251128676f
#define FS1 0.38268343236508977f

__device__ __forceinline__ void bfly(float2& a, float2& b){
  float tx = b.x, ty = b.y;
  b.x = a.x - tx; b.y = a.y - ty;
  a.x += tx;      a.y += ty;
}
__device__ __forceinline__ void cmul_c(float2& b, float wr, float wi){
  float tx = wr*b.x - wi*b.y, ty = wr*b.y + wi*b.x;
  b.x = tx; b.y = ty;
}
__device__ __forceinline__ void rotmi(float2& b){   // b *= -i
  float t = b.x; b.x = b.y; b.y = -t;
}

__device__ __forceinline__ void fft16_reg(float2* v){
  float2 y[16];
  y[0]=v[0];  y[1]=v[8];  y[2]=v[4];  y[3]=v[12];
  y[4]=v[2];  y[5]=v[10]; y[6]=v[6];  y[7]=v[14];
  y[8]=v[1];  y[9]=v[9];  y[10]=v[5]; y[11]=v[13];
  y[12]=v[3]; y[13]=v[11];y[14]=v[7]; y[15]=v[15];
  #pragma unroll
  for (int g = 0; g < 8; g++) bfly(y[2*g], y[2*g+1]);
  #pragma unroll
  for (int g = 0; g < 4; g++){
    int b = 4*g;
    bfly(y[b], y[b+2]);
    rotmi(y[b+3]); bfly(y[b+1], y[b+3]);
  }
  #pragma unroll
  for (int g = 0; g < 2; g++){
    int b = 8*g;
    bfly(y[b], y[b+4]);
    cmul_c(y[b+5],  FC, -FC); bfly(y[b+1], y[b+5]);
    rotmi(y[b+6]);            bfly(y[b+2], y[b+6]);
    cmul_c(y[b+7], -FC, -FC); bfly(y[b+3], y[b+7]);
  }
  bfly(y[0], y[8]);
  cmul_c(y[9],   FC1, -FS1); bfly(y[1], y[9]);
  cmul_c(y[10],  FC,  -FC);  bfly(y[2], y[10]);
  cmul_c(y[11],  FS1, -FC1); bfly(y[3], y[11]);
  rotmi(y[12]);              bfly(y[4], y[12]);
  cmul_c(y[13], -FS1, -FC1); bfly(y[5], y[13]);
  cmul_c(y[14], -FC,  -FC);  bfly(y[6], y[14]);
  cmul_c(y[15], -FC1, -FS1); bfly(y[7], y[15]);
  #pragma unroll
  for (int j = 0; j < 16; j++) v[j] = y[j];
}

__device__ __forceinline__ void fft1024_wave(float2* v, int lane,
                                             const float2* __restrict__ twg){
  #pragma unroll
  for (int s = 0; s < 6; s++){
    const int h = 1 << s;
    const bool up = (lane & h) != 0;
    float2 w = make_float2(1.f, 0.f);
    if (s > 0) w = twg[(lane & (h - 1)) << (9 - s)];
    #pragma unroll
    for (int j = 0; j < 16; j++){
      float ox = __shfl_xor(v[j].x, h, 64);
      float oy = __shfl_xor(v[j].y, h, 64);
      float cx = up ? v[j].x : ox;
      float cy = up ? v[j].y : oy;
      float tx, ty;
      if (s == 0){ tx = cx; ty = cy; }
      else { tx = w.x*cx - w.y*cy; ty = w.x*cy + w.y*cx; }
      v[j].x = up ? (ox - tx) : (v[j].x + tx);
      v[j].y = up ? (oy - ty) : (v[j].y + ty);
    }
  }
  float2 wq = twg[lane];
  float2 cur = make_float2(1.f, 0.f);
  #pragma unroll
  for (int j = 1; j < 16; j++){
    cur = cmulf(cur, wq);
    v[j] = cmulf(v[j], cur);
  }
  fft16_reg(v);
}

// ---------------------------------------------------------------------------
// FFT pass 1 + fused transpose (R7-R10 proven): 512 thr, 8 waves = 8 rows.
// ---------------------------------------------------------------------------
__global__ __launch_bounds__(512)
void fft_rows_t_kernel(const float* __restrict__ pred, const float* __restrict__ targ,
                       float2* __restrict__ Zt, const float2* __restrict__ twg){
  __shared__ float2 tile[4][64][9];
  const int tid = threadIdx.x;
  const int lane = tid & 63;
  const int w = tid >> 6;
  const int y0 = blockIdx.x << 3;
  const size_t ibase = ((size_t)blockIdx.y * HW + (y0 + w)) * HW;
  const int rb = __brev(lane) >> 26;
  const float4* p4 = (const float4*)(pred + ibase);
  const float4* t4 = (const float4*)(targ + ibase);
  float2 v[16];
  #pragma unroll
  for (int m = 0; m < 4; m++){
    float4 a = p4[4*rb + m];
    float4 b = t4[4*rb + m];
    v[4*m+0] = make_float2(a.x, b.x);
    v[4*m+1] = make_float2(a.y, b.y);
    v[4*m+2] = make_float2(a.z, b.z);
    v[4*m+3] = make_float2(a.w, b.w);
  }
  fft1024_wave(v, lane, twg);
  float2* zb = Zt + (size_t)blockIdx.y * HW * HW;
  const int yl = tid & 7, kl = tid >> 3;
  #pragma unroll
  for (int jb = 0; jb < 4; jb++){
    __syncthreads();
    #pragma unroll
    for (int jj = 0; jj < 4; jj++) tile[jj][lane][w] = v[4*jb + jj];
    __syncthreads();
    #pragma unroll
    for (int jj = 0; jj < 4; jj++){
      int k = ((jb << 2) + jj) * 64 + kl;
      zb[(size_t)k * HW + y0 + yl] = tile[jj][kl][yl];
    }
  }
}

// ---------------------------------------------------------------------------
// Cols task (R7/R8-proven register/shfl version, zero LDS): one wave per
// row-pair (a, -a); Hermitian partner via fixed cross-lane permutation.
// ---------------------------------------------------------------------------
__device__ __forceinline__ void freq_contrib(float2 Zk, float2 Zm, int k1, int k2,
                                             float& ms, float& ps){
  int di = k1 - 512, dj = k2 - 512;
  if (di*di + dj*dj < 94372) return;         // dist > 307.2  <=>  r2 >= 94372
  float pr = 0.5f*(Zk.x + Zm.x);
  float pi = 0.5f*(Zk.y - Zm.y);
  float tr = 0.5f*(Zk.y + Zm.y);
  float ti = 0.5f*(Zm.x - Zk.x);
  float p2 = pr*pr + pi*pi;
  float t2 = tr*tr + ti*ti;
  ms += p2 + t2 - 2.f*sqrtf(p2*t2);
  float re = pr*tr + pi*ti;
  float im = pi*tr - pr*ti;
  float pd = fast_atan2f(im, re);
  ps += pd*pd;
}

__device__ void cols_task(const float2* __restrict__ base,
                          const float2* __restrict__ twg,
                          double* __restrict__ acc, int a, int slot){
  const int lane = threadIdx.x & 63;
  const int ap = (1024 - a) & 1023;
  const int rb = __brev(lane) >> 26;
  float2 va[16], vb[16];
  const float4* ra = (const float4*)(base + (size_t)a  * HW);
  const float4* rp = (const float4*)(base + (size_t)ap * HW);
  #pragma unroll
  for (int m = 0; m < 8; m++){
    float4 x = ra[8*rb + m];
    va[2*m]   = make_float2(x.x, x.y);
    va[2*m+1] = make_float2(x.z, x.w);
    float4 yv = rp[8*rb + m];
    vb[2*m]   = make_float2(yv.x, yv.y);
    vb[2*m+1] = make_float2(yv.z, yv.w);
  }
  fft1024_wave(va, lane, twg);
  fft1024_wave(vb, lane, twg);

  float ms = 0.f, ps = 0.f;
  const bool two = (a != ap);                // self-paired rows 0 and 512
  const int qm = (64 - lane) & 63;
  #pragma unroll
  for (int j = 0; j < 16; j++){
    int k = lane + (j << 6);
    float2 shb = make_float2(__shfl(vb[15-j].x, qm, 64), __shfl(vb[15-j].y, qm, 64));
    float2 vbm = (lane == 0) ? vb[(16-j) & 15] : shb;
    freq_contrib(va[j], vbm, k, a, ms, ps);
    if (two){
      float2 sha = make_float2(__shfl(va[15-j].x, qm, 64), __shfl(va[15-j].y, qm, 64));
      float2 vam = (lane == 0) ? va[(16-j) & 15] : sha;
      freq_contrib(vb[j], vam, k, ap, ms, ps);
    }
  }
  #pragma unroll
  for (int o = 32; o > 0; o >>= 1){
    ms += __shfl_down(ms, o, 64);
    ps += __shfl_down(ps, o, 64);
  }
  if (lane == 0){
    atomicAdd(&acc[3*NSLOT + slot], (double)ms);
    atomicAdd(&acc[4*NSLOT + slot], (double)ps);
  }
}

// ---------------------------------------------------------------------------
// Spatial task (verified R4-R10): one 32x32 tile, 4 px/thread. Smem via ptr.
// ---------------------------------------------------------------------------
struct SpatialSmem {
  float sp[36*37];
  float st[36*37];
  float smkf[38*39];
  unsigned long long mrow[38];
  float pmg[34*35];
  float tmg[34*35];
  float sc[4];
};

__device__ void spatial_task(const float* __restrict__ pred,
                             const float* __restrict__ targ,
                             const float* __restrict__ mask,
                             double* __restrict__ acc,
                             int x0, int y0, int z, int slot, SpatialSmem* S){
  float* sp = S->sp; float* st = S->st; float* smkf = S->smkf;
  unsigned long long* mrow = S->mrow;
  float* pmg = S->pmg; float* tmg = S->tmg;
  const int tid = threadIdx.x;
  const size_t ib = (size_t)z * ((size_t)HW * HW);

  for (int i = tid; i < 1296; i += 256){
    int a = i / 36, b = i % 36;
    int gy = y0 - 2 + a, gx = x0 - 2 + b;
    float pv = 0.f, tv = 0.f;
    if ((unsigned)gy < HW && (unsigned)gx < HW){
      size_t idx = ib + (size_t)gy * HW + gx;
      pv = pred[idx]; tv = targ[idx];
    }
    sp[a*37+b] = pv; st[a*37+b] = tv;
  }
  for (int i = tid; i < 1444; i += 256){
    int a = i / 38, b = i % 38;
    int gy = y0 - 3 + a, gx = x0 - 3 + b;
    float v = 0.f;
    if ((unsigned)gy < HW && (unsigned)gx < HW) v = mask[ib + (size_t)gy * HW + gx];
    smkf[a*39+b] = v;
  }
  __syncthreads();

  if (tid < 38){
    unsigned long long w = 0ull;
    #pragma unroll
    for (int x = 0; x < 38; x++)
      w |= (smkf[tid*39 + x] > 0.5f) ? (1ull << x) : 0ull;
    mrow[tid] = w;
  }

  for (int i = tid; i < 1156; i += 256){
    int iy = i / 34, ix = i % 34;
    int gy = y0 - 1 + iy, gx = x0 - 1 + ix;
    float pv = 0.f, tv = 0.f;
    if ((unsigned)gy < HW && (unsigned)gx < HW){
      int o = (iy)*37 + ix;
      float a00=sp[o], a01=sp[o+1], a02=sp[o+2];
      float a10=sp[o+37],           a12=sp[o+39];
      float a20=sp[o+74], a21=sp[o+75], a22=sp[o+76];
      float gxp = (a02 + 2.f*a12 + a22) - (a00 + 2.f*a10 + a20);
      float gyp = (a20 + 2.f*a21 + a22) - (a00 + 2.f*a01 + a02);
      pv = sqrtf(gxp*gxp + gyp*gyp + 1e-8f);
      float b00=st[o], b01=st[o+1], b02=st[o+2];
      float b10=st[o+37],           b12=st[o+39];
      float b20=st[o+74], b21=st[o+75], b22=st[o+76];
      float gxt = (b02 + 2.f*b12 + b22) - (b00 + 2.f*b10 + b20);
      float gyt = (b20 + 2.f*b21 + b22) - (b00 + 2.f*b01 + b02);
      tv = sqrtf(gxt*gxt + gyt*gyt + 1e-8f);
    }
    pmg[iy*35+ix] = pv; tmg[iy*35+ix] = tv;
  }
  __syncthreads();

  const int ty = tid >> 5, tx = tid & 31;
  const int r0 = ty << 2;

  int c1[10], c2[10], c3[10];
  #pragma unroll
  for (int j = 0; j < 10; j++){
    unsigned w = (unsigned)(mrow[r0 + j] >> tx);
    c3[j] = __popc(w & 0x7Fu);
    c2[j] = __popc((w >> 1) & 0x1Fu);
    c1[j] = __popc((w >> 2) & 0x7u);
  }

  float P[3][3], Q[3][3], A[3][3], B[3][3];
  #pragma unroll
  for (int rr = 0; rr < 3; rr++)
    #pragma unroll
    for (int cc = 0; cc < 3; cc++){
      P[rr][cc] = sp[(r0+1+rr)*37 + tx+1+cc];
      Q[rr][cc] = st[(r0+1+rr)*37 + tx+1+cc];
      A[rr][cc] = pmg[(r0+rr)*35 + tx+cc];
      B[rr][cc] = tmg[(r0+rr)*35 + tx+cc];
    }

  float accg = 0.f, accs = 0.f, accl = 0.f;
  #pragma unroll
  for (int k = 0; k < 4; k++){
    if (k){
      #pragma unroll
      for (int cc = 0; cc < 3; cc++){
        P[0][cc]=P[1][cc]; P[1][cc]=P[2][cc]; P[2][cc]=sp[(r0+k+3)*37 + tx+1+cc];
        Q[0][cc]=Q[1][cc]; Q[1][cc]=Q[2][cc]; Q[2][cc]=st[(r0+k+3)*37 + tx+1+cc];
        A[0][cc]=A[1][cc]; A[1][cc]=A[2][cc]; A[2][cc]=pmg[(r0+k+2)*35 + tx+cc];
        B[0][cc]=B[1][cc]; B[1][cc]=B[2][cc]; B[2][cc]=tmg[(r0+k+2)*35 + tx+cc];
      }
    }
    float gxp = (P[0][2]+2.f*P[1][2]+P[2][2]) - (P[0][0]+2.f*P[1][0]+P[2][0]);
    float gyp = (P[2][0]+2.f*P[2][1]+P[2][2]) - (P[0][0]+2.f*P[0][1]+P[0][2]);
    float cvp = 4.f*P[1][1] - P[0][1] - P[1][0] - P[1][2] - P[2][1];
    float gxt = (Q[0][2]+2.f*Q[1][2]+Q[2][2]) - (Q[0][0]+2.f*Q[1][0]+Q[2][0]);
    float gyt = (Q[2][0]+2.f*Q[2][1]+Q[2][2]) - (Q[0][0]+2.f*Q[0][1]+Q[0][2]);
    float cvt = 4.f*Q[1][1] - Q[0][1] - Q[1][0] - Q[1][2] - Q[2][1];

    float sd = fabsf(A[1][1] - B[1][1]);
    float x1 = gxp + 1e-8f, y1 = gyp;
    float x2 = gxt + 1e-8f, y2 = gyt;
    float dd = fabsf(fast_atan2f(y1*x2 - x1*y2, x1*x2 + y1*y2));
    float cd = fabsf(cvp - cvt);

    int s1 = c1[k+2]+c1[k+3]+c1[k+4];
    int s2 = c2[k+1]+c2[k+2]+c2[k+3]+c2[k+4]+c2[k+5];
    int s3 = c3[k]+c3[k+1]+c3[k+2]+c3[k+3]+c3[k+4]+c3[k+5]+c3[k+6];
    float w1 = (s1 > 0 && s1 <  9) ? 1.f : 0.f;
    float w2 = (s2 > 0 && s2 < 25) ? 1.f : 0.f;
    float w3 = (s3 > 0 && s3 < 49) ? 1.f : 0.f;

    accg += (sd + dd) * (w1 + 0.5f*(w2 + w3)) + cd * (2.f*w1 + w2 + w3);

    float s9 = 0.f, s9q = 0.f;
    #pragma unroll
    for (int rr = 0; rr < 3; rr++)
      #pragma unroll
      for (int cc = 0; cc < 3; cc++){ s9 += P[rr][cc]; s9q += P[rr][cc]*P[rr][cc]; }
    float lm = s9 * (1.f/9.f), lq = s9q * (1.f/9.f);
    accs += sqrtf(fmaxf(lq - lm*lm, 1e-8f)) * w1;

    float psx = (A[0][2]+2.f*A[1][2]+A[2][2]) - (A[0][0]+2.f*A[1][0]+A[2][0]);
    float psy = (A[2][0]+2.f*A[2][1]+A[2][2]) - (A[0][0]+2.f*A[0][1]+A[0][2]);
    float pch = sqrtf(psx*psx + psy*psy + 1e-8f);
    float tsx = (B[0][2]+2.f*B[1][2]+B[2][2]) - (B[0][0]+2.f*B[1][0]+B[2][0]);
    float tsy = (B[2][0]+2.f*B[2][1]+B[2][2]) - (B[0][0]+2.f*B[0][1]+B[0][2]);
    float tch = sqrtf(tsx*tsx + tsy*tsy + 1e-8f);
    accl += fabsf(pch - tch) * w1;
  }

  float g  = block_reduce_add_f(accg, S->sc);
  float sm = block_reduce_add_f(accs, S->sc);
  float sl = block_reduce_add_f(accl, S->sc);
  if (tid == 0){
    atomicAdd(&acc[0*NSLOT + slot], (double)g);
    atomicAdd(&acc[1*NSLOT + slot], (double)sm);
    atomicAdd(&acc[2*NSLOT + slot], (double)sl);
  }
}

// ---------------------------------------------------------------------------
// Fused cols + spatial: blocks [0,1032) = col-FFT+reduce (4 pair-tasks/block,
// 129 blocks x 8 images); blocks [1032, 1032+8192) = spatial tiles. cols
// first so its latency-bound waves are resident before the VALU flood (m114:
// co-scheduled VALU+memory waves run in max(), not sum). No min-waves bound
// (R9 lesson: forcing 128-VGPR cap spills the cols role).
// ---------------------------------------------------------------------------
__global__ __launch_bounds__(256)
void fused_cols_spatial(const float* __restrict__ pred, const float* __restrict__ targ,
                        const float* __restrict__ mask, const float2* __restrict__ Z,
                        const float2* __restrict__ twg, double* __restrict__ acc){
  __shared__ __align__(16) unsigned char smem[sizeof(SpatialSmem)];
  const int bx = blockIdx.x;
  if (bx < 1032){
    int img = bx / 129;
    int loc = bx - img * 129;
    int a = (loc << 2) + (threadIdx.x >> 6);
    if (a <= 512){
      const float2* base = Z + (size_t)img * HW * HW;
      cols_task(base, twg, acc, a, (a + img * 11) & (NSLOT - 1));
    }
  } else {
    int l = bx - 1032;
    int x0 = (l & 31) << 5, y0 = ((l >> 5) & 31) << 5, z = l >> 10;
    spatial_task(pred, targ, mask, acc, x0, y0, z,
                 ((l & 1023) * 7 + z * 13) & (NSLOT - 1), (SpatialSmem*)smem);
  }
}

// ---------------------------------------------------------------------------
__global__ void finalize_kernel(const double* __restrict__ acc, float* __restrict__ out){
  const int t = threadIdx.x;   // 64 threads
  double v[5];
  #pragma unroll
  for (int s = 0; s < 5; s++) v[s] = acc[s*NSLOT + t];
  #pragma unroll
  for (int o = 32; o > 0; o >>= 1)
    #pragma unroll
    for (int s = 0; s < 5; s++) v[s] += __shfl_down(v[s], o, 64);
  if (t == 0){
    const double inv = 1.0 / 8388608.0;      // mean over 8*1024*1024
    double grad   = v[0] * inv / 3.0;        // / len(bms)
    double smooth = v[1] * inv;
    double slope  = v[2] * inv;
    double freq   = (v[3] + 2.0 * v[4]) * inv;
    double total  = 2.0*grad + 1.5*freq + 3.0*smooth + 2.0*slope;
    out[0] = (float)total;
    out[1] = (float)grad;
    out[2] = (float)freq;
    out[3] = (float)smooth;
    out[4] = (float)slope;
  }
}

extern "C" void kernel_launch(void* const* d_in, const int* in_sizes, int n_in,
                              void* d_out, int out_size, void* d_ws, size_t ws_size,
                              hipStream_t stream){
  const float* pred = (const float*)d_in[0];
  const float* targ = (const float*)d_in[1];
  const float* mask = (const float*)d_in[2];
  double* acc = (double*)d_ws;                          // [0, 2560)
  float2* twg = (float2*)((char*)d_ws + 4096);          // [4096, 8192)
  float2* Z   = (float2*)((char*)d_ws + 8192);          // 8 x 8 MiB fp32 images
  // ws_size measured ~256 MiB (R9 fill profile) — 64 MiB Z fits with margin.

  setup_kernel<<<2, 256, 0, stream>>>(acc, twg);
  // rows must complete before cols reads Zt; spatial is independent and rides
  // in the same dispatch as cols to co-schedule VALU with FFT memory waves.
  fft_rows_t_kernel<<<dim3(128, 8), 512, 0, stream>>>(pred, targ, Z, twg);
  fused_cols_spatial<<<1032 + 8192, 256, 0, stream>>>(pred, targ, mask, Z, twg, acc);
  finalize_kernel<<<1, 64, 0, stream>>>(acc, (float*)d_out);
}

// Round 13
// 269.472 us; speedup vs baseline: 1.1291x; 1.1291x over previous
//
#include <hip/hip_runtime.h>
#include <hip/hip_fp16.h>

#define HW 1024
#define TWO_PI_F 6.28318530717958647692f
#define NSLOT 64   // atomic spreading: 64 slots per accumulator, 5 accumulators

__device__ __forceinline__ float2 cmulf(float2 a, float2 b){
  return make_float2(a.x*b.x - a.y*b.y, a.x*b.y + a.y*b.x);
}
__device__ __forceinline__ float fsqrt(float x){ return __builtin_amdgcn_sqrtf(x); }

// fast atan2: octant reduction + 9th-order odd minimax poly, max err ~1e-4 rad.
__device__ __forceinline__ float fast_atan2f(float y, float x){
  float ax = fabsf(x), ay = fabsf(y);
  float mx = fmaxf(ax, ay), mn = fminf(ax, ay);
  float a  = mn * __builtin_amdgcn_rcpf(fmaxf(mx, 1e-37f));
  float s  = a * a;
  float r  = ((((0.0208351f*s - 0.085133f)*s + 0.180141f)*s - 0.3302995f)*s
              + 0.999866f) * a;
  r = (ay > ax) ? 1.57079632679f - r : r;
  r = (x < 0.f) ? 3.14159265359f - r : r;
  return (y < 0.f) ? -r : r;
}

// 256-thread block reduction (4 waves of 64), float
__device__ __forceinline__ float block_reduce_add_f(float v, float* sc){
  int tid = threadIdx.x;
  #pragma unroll
  for (int o = 32; o > 0; o >>= 1) v += __shfl_down(v, o, 64);
  __syncthreads();
  if ((tid & 63) == 0) sc[tid >> 6] = v;
  __syncthreads();
  return sc[0] + sc[1] + sc[2] + sc[3];
}

// merged setup: zero accumulators + twiddle table (one launch)
__global__ void setup_kernel(double* acc, float2* twg){
  int i = threadIdx.x + blockIdx.x * 256;   // grid 2 x 256 -> 0..511
  if (i < 5 * NSLOT) acc[i] = 0.0;
  if (i < 512){
    float s, c; sincosf(-TWO_PI_F * (float)i * (1.f/1024.f), &s, &c);
    twg[i] = make_float2(c, s);
  }
}

// ---------------------------------------------------------------------------
// Spatial half (verified R4-R11): 32x32 tile/block, 4 px/thread, one dispatch.
// ---------------------------------------------------------------------------
__global__ __launch_bounds__(256)
void spatial_kernel(const float* __restrict__ pred, const float* __restrict__ targ,
                    const float* __restrict__ mask, double* __restrict__ acc){
  __shared__ float sp[36*37];
  __shared__ float st[36*37];
  __shared__ float smkf[38*39];
  __shared__ unsigned long long mrow[38];
  __shared__ float pmg[34*35];
  __shared__ float tmg[34*35];
  __shared__ float sc[4];

  const int tid = threadIdx.x;
  const int x0 = blockIdx.x << 5, y0 = blockIdx.y << 5;
  const int z = blockIdx.z;
  const size_t ib = (size_t)z * ((size_t)HW * HW);

  for (int i = tid; i < 1296; i += 256){
    int a = i / 36, b = i % 36;
    int gy = y0 - 2 + a, gx = x0 - 2 + b;
    float pv = 0.f, tv = 0.f;
    if ((unsigned)gy < HW && (unsigned)gx < HW){
      size_t idx = ib + (size_t)gy * HW + gx;
      pv = pred[idx]; tv = targ[idx];
    }
    sp[a*37+b] = pv; st[a*37+b] = tv;
  }
  for (int i = tid; i < 1444; i += 256){
    int a = i / 38, b = i % 38;
    int gy = y0 - 3 + a, gx = x0 - 3 + b;
    float v = 0.f;
    if ((unsigned)gy < HW && (unsigned)gx < HW) v = mask[ib + (size_t)gy * HW + gx];
    smkf[a*39+b] = v;
  }
  __syncthreads();

  if (tid < 38){
    unsigned long long w = 0ull;
    #pragma unroll
    for (int x = 0; x < 38; x++)
      w |= (smkf[tid*39 + x] > 0.5f) ? (1ull << x) : 0ull;
    mrow[tid] = w;
  }

  for (int i = tid; i < 1156; i += 256){
    int iy = i / 34, ix = i % 34;
    int gy = y0 - 1 + iy, gx = x0 - 1 + ix;
    float pv = 0.f, tv = 0.f;
    if ((unsigned)gy < HW && (unsigned)gx < HW){
      int o = (iy)*37 + ix;
      float a00=sp[o], a01=sp[o+1], a02=sp[o+2];
      float a10=sp[o+37],           a12=sp[o+39];
      float a20=sp[o+74], a21=sp[o+75], a22=sp[o+76];
      float gxp = (a02 + 2.f*a12 + a22) - (a00 + 2.f*a10 + a20);
      float gyp = (a20 + 2.f*a21 + a22) - (a00 + 2.f*a01 + a02);
      pv = fsqrt(gxp*gxp + gyp*gyp + 1e-8f);
      float b00=st[o], b01=st[o+1], b02=st[o+2];
      float b10=st[o+37],           b12=st[o+39];
      float b20=st[o+74], b21=st[o+75], b22=st[o+76];
      float gxt = (b02 + 2.f*b12 + b22) - (b00 + 2.f*b10 + b20);
      float gyt = (b20 + 2.f*b21 + b22) - (b00 + 2.f*b01 + b02);
      tv = fsqrt(gxt*gxt + gyt*gyt + 1e-8f);
    }
    pmg[iy*35+ix] = pv; tmg[iy*35+ix] = tv;
  }
  __syncthreads();

  const int ty = tid >> 5, tx = tid & 31;
  const int r0 = ty << 2;

  int c1[10], c2[10], c3[10];
  #pragma unroll
  for (int j = 0; j < 10; j++){
    unsigned w = (unsigned)(mrow[r0 + j] >> tx);
    c3[j] = __popc(w & 0x7Fu);
    c2[j] = __popc((w >> 1) & 0x1Fu);
    c1[j] = __popc((w >> 2) & 0x7u);
  }

  float P[3][3], Q[3][3], A[3][3], B[3][3];
  #pragma unroll
  for (int rr = 0; rr < 3; rr++)
    #pragma unroll
    for (int cc = 0; cc < 3; cc++){
      P[rr][cc] = sp[(r0+1+rr)*37 + tx+1+cc];
      Q[rr][cc] = st[(r0+1+rr)*37 + tx+1+cc];
      A[rr][cc] = pmg[(r0+rr)*35 + tx+cc];
      B[rr][cc] = tmg[(r0+rr)*35 + tx+cc];
    }

  float accg = 0.f, accs = 0.f, accl = 0.f;
  #pragma unroll
  for (int k = 0; k < 4; k++){
    if (k){
      #pragma unroll
      for (int cc = 0; cc < 3; cc++){
        P[0][cc]=P[1][cc]; P[1][cc]=P[2][cc]; P[2][cc]=sp[(r0+k+3)*37 + tx+1+cc];
        Q[0][cc]=Q[1][cc]; Q[1][cc]=Q[2][cc]; Q[2][cc]=st[(r0+k+3)*37 + tx+1+cc];
        A[0][cc]=A[1][cc]; A[1][cc]=A[2][cc]; A[2][cc]=pmg[(r0+k+2)*35 + tx+cc];
        B[0][cc]=B[1][cc]; B[1][cc]=B[2][cc]; B[2][cc]=tmg[(r0+k+2)*35 + tx+cc];
      }
    }
    float gxp = (P[0][2]+2.f*P[1][2]+P[2][2]) - (P[0][0]+2.f*P[1][0]+P[2][0]);
    float gyp = (P[2][0]+2.f*P[2][1]+P[2][2]) - (P[0][0]+2.f*P[0][1]+P[0][2]);
    float cvp = 4.f*P[1][1] - P[0][1] - P[1][0] - P[1][2] - P[2][1];
    float gxt = (Q[0][2]+2.f*Q[1][2]+Q[2][2]) - (Q[0][0]+2.f*Q[1][0]+Q[2][0]);
    float gyt = (Q[2][0]+2.f*Q[2][1]+Q[2][2]) - (Q[0][0]+2.f*Q[0][1]+Q[0][2]);
    float cvt = 4.f*Q[1][1] - Q[0][1] - Q[1][0] - Q[1][2] - Q[2][1];

    float sd = fabsf(A[1][1] - B[1][1]);
    float x1 = gxp + 1e-8f, y1 = gyp;
    float x2 = gxt + 1e-8f, y2 = gyt;
    float dd = fabsf(fast_atan2f(y1*x2 - x1*y2, x1*x2 + y1*y2));
    float cd = fabsf(cvp - cvt);

    int s1 = c1[k+2]+c1[k+3]+c1[k+4];
    int s2 = c2[k+1]+c2[k+2]+c2[k+3]+c2[k+4]+c2[k+5];
    int s3 = c3[k]+c3[k+1]+c3[k+2]+c3[k+3]+c3[k+4]+c3[k+5]+c3[k+6];
    float w1 = (s1 > 0 && s1 <  9) ? 1.f : 0.f;
    float w2 = (s2 > 0 && s2 < 25) ? 1.f : 0.f;
    float w3 = (s3 > 0 && s3 < 49) ? 1.f : 0.f;

    accg += (sd + dd) * (w1 + 0.5f*(w2 + w3)) + cd * (2.f*w1 + w2 + w3);

    float s9 = 0.f, s9q = 0.f;
    #pragma unroll
    for (int rr = 0; rr < 3; rr++)
      #pragma unroll
      for (int cc = 0; cc < 3; cc++){ s9 += P[rr][cc]; s9q += P[rr][cc]*P[rr][cc]; }
    float lm = s9 * (1.f/9.f), lq = s9q * (1.f/9.f);
    accs += fsqrt(fmaxf(lq - lm*lm, 1e-8f)) * w1;

    float psx = (A[0][2]+2.f*A[1][2]+A[2][2]) - (A[0][0]+2.f*A[1][0]+A[2][0]);
    float psy = (A[2][0]+2.f*A[2][1]+A[2][2]) - (A[0][0]+2.f*A[0][1]+A[0][2]);
    float pch = fsqrt(psx*psx + psy*psy + 1e-8f);
    float tsx = (B[0][2]+2.f*B[1][2]+B[2][2]) - (B[0][0]+2.f*B[1][0]+B[2][0]);
    float tsy = (B[2][0]+2.f*B[2][1]+B[2][2]) - (B[0][0]+2.f*B[0][1]+B[0][2]);
    float tch = fsqrt(tsx*tsx + tsy*tsy + 1e-8f);
    accl += fabsf(pch - tch) * w1;
  }

  float g  = block_reduce_add_f(accg, sc);
  float sm = block_reduce_add_f(accs, sc);
  float sl = block_reduce_add_f(accl, sc);
  if (tid == 0){
    int slot = (blockIdx.x + blockIdx.y * 7 + z * 13) & (NSLOT - 1);
    atomicAdd(&acc[0*NSLOT + slot], (double)g);
    atomicAdd(&acc[1*NSLOT + slot], (double)sm);
    atomicAdd(&acc[2*NSLOT + slot], (double)sl);
  }
}

// ---------------------------------------------------------------------------
// Lane-xor exchange with cheap routing: DPP (VALU pipe) for h=1,2,8;
// ds_swizzle for h=4,16; bpermute only for h=32.
//   quad_perm [1,0,3,2] = 0xB1 (xor1); [2,3,0,1] = 0x4E (xor2);
//   row_ror:8 = 0x128 (xor8 within rows of 16, since ror8 == xor8 mod 16).
// ---------------------------------------------------------------------------
__device__ __forceinline__ float lane_xor(float x, int h, int lane){
  int xi = __float_as_int(x);
  int r;
  if (h == 1)       r = __builtin_amdgcn_update_dpp(xi, xi, 0xB1, 0xF, 0xF, true);
  else if (h == 2)  r = __builtin_amdgcn_update_dpp(xi, xi, 0x4E, 0xF, 0xF, true);
  else if (h == 8)  r = __builtin_amdgcn_update_dpp(xi, xi, 0x128, 0xF, 0xF, true);
  else if (h == 4)  r = __builtin_amdgcn_ds_swizzle(xi, 0x101F);  // xor4
  else if (h == 16) r = __builtin_amdgcn_ds_swizzle(xi, 0x401F);  // xor16
  else              r = __builtin_amdgcn_ds_bpermute((lane ^ 32) << 2, xi);
  return __int_as_float(r);
}

// ---------------------------------------------------------------------------
// Wave-level 1024-pt FFT (verified R6-R11): 64 (cross-lane) x 16 (in-register).
// Input: lane q, slot j holds x[j + 16*brev6(q)]. Output: slot j = X[q + 64*j].
// ---------------------------------------------------------------------------
#define FC 0.70710678118654752f
#define FC1 0.92387953251128676f
#define FS1 0.38268343236508977f

__device__ __forceinline__ void bfly(float2& a, float2& b){
  float tx = b.x, ty = b.y;
  b.x = a.x - tx; b.y = a.y - ty;
  a.x += tx;      a.y += ty;
}
__device__ __forceinline__ void cmul_c(float2& b, float wr, float wi){
  float tx = wr*b.x - wi*b.y, ty = wr*b.y + wi*b.x;
  b.x = tx; b.y = ty;
}
__device__ __forceinline__ void rotmi(float2& b){   // b *= -i
  float t = b.x; b.x = b.y; b.y = -t;
}

__device__ __forceinline__ void fft16_reg(float2* v){
  float2 y[16];
  y[0]=v[0];  y[1]=v[8];  y[2]=v[4];  y[3]=v[12];
  y[4]=v[2];  y[5]=v[10]; y[6]=v[6];  y[7]=v[14];
  y[8]=v[1];  y[9]=v[9];  y[10]=v[5]; y[11]=v[13];
  y[12]=v[3]; y[13]=v[11];y[14]=v[7]; y[15]=v[15];
  #pragma unroll
  for (int g = 0; g < 8; g++) bfly(y[2*g], y[2*g+1]);
  #pragma unroll
  for (int g = 0; g < 4; g++){
    int b = 4*g;
    bfly(y[b], y[b+2]);
    rotmi(y[b+3]); bfly(y[b+1], y[b+3]);
  }
  #pragma unroll
  for (int g = 0; g < 2; g++){
    int b = 8*g;
    bfly(y[b], y[b+4]);
    cmul_c(y[b+5],  FC, -FC); bfly(y[b+1], y[b+5]);
    rotmi(y[b+6]);            bfly(y[b+2], y[b+6]);
    cmul_c(y[b+7], -FC, -FC); bfly(y[b+3], y[b+7]);
  }
  bfly(y[0], y[8]);
  cmul_c(y[9],   FC1, -FS1); bfly(y[1], y[9]);
  cmul_c(y[10],  FC,  -FC);  bfly(y[2], y[10]);
  cmul_c(y[11],  FS1, -FC1); bfly(y[3], y[11]);
  rotmi(y[12]);              bfly(y[4], y[12]);
  cmul_c(y[13], -FS1, -FC1); bfly(y[5], y[13]);
  cmul_c(y[14], -FC,  -FC);  bfly(y[6], y[14]);
  cmul_c(y[15], -FC1, -FS1); bfly(y[7], y[15]);
  #pragma unroll
  for (int j = 0; j < 16; j++) v[j] = y[j];
}

__device__ __forceinline__ void fft1024_wave(float2* v, int lane,
                                             const float2* __restrict__ twg){
  #pragma unroll
  for (int s = 0; s < 6; s++){
    const int h = 1 << s;
    const bool up = (lane & h) != 0;
    float2 w = make_float2(1.f, 0.f);
    if (s > 0) w = twg[(lane & (h - 1)) << (9 - s)];
    #pragma unroll
    for (int j = 0; j < 16; j++){
      float ox = lane_xor(v[j].x, h, lane);
      float oy = lane_xor(v[j].y, h, lane);
      float cx = up ? v[j].x : ox;
      float cy = up ? v[j].y : oy;
      float tx, ty;
      if (s == 0){ tx = cx; ty = cy; }
      else { tx = w.x*cx - w.y*cy; ty = w.x*cy + w.y*cx; }
      v[j].x = up ? (ox - tx) : (v[j].x + tx);
      v[j].y = up ? (oy - ty) : (v[j].y + ty);
    }
  }
  float2 wq = twg[lane];
  float2 cur = make_float2(1.f, 0.f);
  #pragma unroll
  for (int j = 1; j < 16; j++){
    cur = cmulf(cur, wq);
    v[j] = cmulf(v[j], cur);
  }
  fft16_reg(v);
}

// ---------------------------------------------------------------------------
// FFT pass 1 + fused transpose, fp16 Zt out: 512 thr, 8 waves = 8 rows.
// Zt element = half2(re, im), 4 B; image = 4 MiB.
// ---------------------------------------------------------------------------
__global__ __launch_bounds__(512)
void fft_rows_t_kernel(const float* __restrict__ pred, const float* __restrict__ targ,
                       __half2* __restrict__ Zt, const float2* __restrict__ twg){
  __shared__ float2 tile[4][64][9];
  const int tid = threadIdx.x;
  const int lane = tid & 63;
  const int w = tid >> 6;
  const int y0 = blockIdx.x << 3;
  const size_t ibase = ((size_t)blockIdx.y * HW + (y0 + w)) * HW;
  const int rb = __brev(lane) >> 26;
  const float4* p4 = (const float4*)(pred + ibase);
  const float4* t4 = (const float4*)(targ + ibase);
  float2 v[16];
  #pragma unroll
  for (int m = 0; m < 4; m++){
    float4 a = p4[4*rb + m];
    float4 b = t4[4*rb + m];
    v[4*m+0] = make_float2(a.x, b.x);
    v[4*m+1] = make_float2(a.y, b.y);
    v[4*m+2] = make_float2(a.z, b.z);
    v[4*m+3] = make_float2(a.w, b.w);
  }
  fft1024_wave(v, lane, twg);
  __half2* zb = Zt + (size_t)blockIdx.y * HW * HW;
  const int yl = tid & 7, kl = tid >> 3;
  #pragma unroll
  for (int jb = 0; jb < 4; jb++){
    __syncthreads();
    #pragma unroll
    for (int jj = 0; jj < 4; jj++) tile[jj][lane][w] = v[4*jb + jj];
    __syncthreads();
    #pragma unroll
    for (int jj = 0; jj < 4; jj++){
      int k = ((jb << 2) + jj) * 64 + kl;
      float2 e = tile[jj][kl][yl];
      zb[(size_t)k * HW + y0 + yl] = __floats2half2_rn(e.x, e.y);
    }
  }
}

// ---------------------------------------------------------------------------
// FFT pass 2 + reduce (R10-proven structure): one FFT per wave, Hermitian
// partner via natural-order LDS; fp16 Zt in. FIX vs R12: a uint4 holds FOUR
// half2 (16 B), so each lane reads 4 uint4 (m=0..3) to get its 16 elements.
// ---------------------------------------------------------------------------
__device__ __forceinline__ void freq_contrib(float2 Zk, float2 Zm, int k1, int k2,
                                             float& ms, float& ps){
  int di = k1 - 512, dj = k2 - 512;
  if (di*di + dj*dj < 94372) return;         // dist > 307.2  <=>  r2 >= 94372
  float pr = 0.5f*(Zk.x + Zm.x);
  float pi = 0.5f*(Zk.y - Zm.y);
  float tr = 0.5f*(Zk.y + Zm.y);
  float ti = 0.5f*(Zm.x - Zk.x);
  float p2 = pr*pr + pi*pi;
  float t2 = tr*tr + ti*ti;
  ms += p2 + t2 - 2.f*fsqrt(p2*t2);
  float re = pr*tr + pi*ti;
  float im = pi*tr - pr*ti;
  float pd = fast_atan2f(im, re);
  ps += pd*pd;
}

__global__ __launch_bounds__(256)
void fft_cols2_kernel(const __half2* __restrict__ Z, const float2* __restrict__ twg,
                      double* __restrict__ acc){
  __shared__ float2 ex[4][1024];            // per-wave natural-order spectrum
  const int lane = threadIdx.x & 63;
  const int w = threadIdx.x >> 6;           // 0..3
  const int p = 2 * blockIdx.x + (w >> 1);  // pair index, 0..512 valid
  const bool valid = (p <= 512);
  const int r = (w & 1) ? ((1024 - p) & 1023) : p;   // this wave's Zt row
  const __half2* base = Z + (size_t)blockIdx.y * HW * HW;
  const int rb = __brev(lane) >> 26;

  float2 v[16];
  if (valid){
    const uint4* rr = (const uint4*)(base + (size_t)r * HW);
    #pragma unroll
    for (int m = 0; m < 4; m++){
      union { uint4 u; __half2 h[4]; } x;
      x.u = rr[4*rb + m];
      #pragma unroll
      for (int t = 0; t < 4; t++) v[4*m+t] = __half22float2(x.h[t]);
    }
    fft1024_wave(v, lane, twg);
    #pragma unroll
    for (int j = 0; j < 16; j++) ex[w][lane + (j << 6)] = v[j];
  }
  __syncthreads();
  if (!valid) return;
  const bool self = (p == 0) || (p == 512);
  if ((w & 1) && self) return;              // duplicate row: LDS written, no contribs

  const float2* pb = ex[w ^ 1];             // partner spectrum, natural order
  float ms = 0.f, ps = 0.f;
  #pragma unroll
  for (int j = 0; j < 16; j++){
    int k = lane + (j << 6);
    float2 zm = pb[(1024 - k) & 1023];      // Z_partner(-k)
    freq_contrib(v[j], zm, k, r, ms, ps);
  }
  #pragma unroll
  for (int o = 32; o > 0; o >>= 1){
    ms += __shfl_down(ms, o, 64);
    ps += __shfl_down(ps, o, 64);
  }
  if (lane == 0){
    int slot = (r + blockIdx.y * 11) & (NSLOT - 1);
    atomicAdd(&acc[3*NSLOT + slot], (double)ms);
    atomicAdd(&acc[4*NSLOT + slot], (double)ps);
  }
}

// ---------------------------------------------------------------------------
__global__ void finalize_kernel(const double* __restrict__ acc, float* __restrict__ out){
  const int t = threadIdx.x;   // 64 threads
  double v[5];
  #pragma unroll
  for (int s = 0; s < 5; s++) v[s] = acc[s*NSLOT + t];
  #pragma unroll
  for (int o = 32; o > 0; o >>= 1)
    #pragma unroll
    for (int s = 0; s < 5; s++) v[s] += __shfl_down(v[s], o, 64);
  if (t == 0){
    const double inv = 1.0 / 8388608.0;      // mean over 8*1024*1024
    double grad   = v[0] * inv / 3.0;        // / len(bms)
    double smooth = v[1] * inv;
    double slope  = v[2] * inv;
    double freq   = (v[3] + 2.0 * v[4]) * inv;
    double total  = 2.0*grad + 1.5*freq + 3.0*smooth + 2.0*slope;
    out[0] = (float)total;
    out[1] = (float)grad;
    out[2] = (float)freq;
    out[3] = (float)smooth;
    out[4] = (float)slope;
  }
}

extern "C" void kernel_launch(void* const* d_in, const int* in_sizes, int n_in,
                              void* d_out, int out_size, void* d_ws, size_t ws_size,
                              hipStream_t stream){
  const float* pred = (const float*)d_in[0];
  const float* targ = (const float*)d_in[1];
  const float* mask = (const float*)d_in[2];
  double* acc  = (double*)d_ws;                         // [0, 2560)
  float2* twg  = (float2*)((char*)d_ws + 4096);         // [4096, 8192)
  __half2* Z   = (__half2*)((char*)d_ws + 8192);        // 8 x 4 MiB fp16 images
  // ws_size ~256 MiB (measured R9) — 32 MiB Z fits easily.

  setup_kernel<<<2, 256, 0, stream>>>(acc, twg);
  spatial_kernel<<<dim3(32, 32, 8), 256, 0, stream>>>(pred, targ, mask, acc);
  fft_rows_t_kernel<<<dim3(128, 8), 512, 0, stream>>>(pred, targ, Z, twg);
  fft_cols2_kernel<<<dim3(257, 8), 256, 0, stream>>>(Z, twg, acc);
  finalize_kernel<<<1, 64, 0, stream>>>(acc, (float*)d_out);
}

// Round 14
// 267.067 us; speedup vs baseline: 1.1392x; 1.0090x over previous
//
#include <hip/hip_runtime.h>

#define HW 1024
#define TWO_PI_F 6.28318530717958647692f
#define NSLOT 64   // atomic spreading: 64 slots per accumulator, 5 accumulators

__device__ __forceinline__ float2 cmulf(float2 a, float2 b){
  return make_float2(a.x*b.x - a.y*b.y, a.x*b.y + a.y*b.x);
}
__device__ __forceinline__ float fsqrt(float x){ return __builtin_amdgcn_sqrtf(x); }

// fast atan2: octant reduction + 9th-order odd minimax poly, max err ~1e-4 rad.
__device__ __forceinline__ float fast_atan2f(float y, float x){
  float ax = fabsf(x), ay = fabsf(y);
  float mx = fmaxf(ax, ay), mn = fminf(ax, ay);
  float a  = mn * __builtin_amdgcn_rcpf(fmaxf(mx, 1e-37f));
  float s  = a * a;
  float r  = ((((0.0208351f*s - 0.085133f)*s + 0.180141f)*s - 0.3302995f)*s
              + 0.999866f) * a;
  r = (ay > ax) ? 1.57079632679f - r : r;
  r = (x < 0.f) ? 3.14159265359f - r : r;
  return (y < 0.f) ? -r : r;
}

// 256-thread block reduction (4 waves of 64), float
__device__ __forceinline__ float block_reduce_add_f(float v, float* sc){
  int tid = threadIdx.x;
  #pragma unroll
  for (int o = 32; o > 0; o >>= 1) v += __shfl_down(v, o, 64);
  __syncthreads();
  if ((tid & 63) == 0) sc[tid >> 6] = v;
  __syncthreads();
  return sc[0] + sc[1] + sc[2] + sc[3];
}

// merged setup: zero accumulators + twiddle table (one launch)
__global__ void setup_kernel(double* acc, float2* twg){
  int i = threadIdx.x + blockIdx.x * 256;   // grid 2 x 256 -> 0..511
  if (i < 5 * NSLOT) acc[i] = 0.0;
  if (i < 512){
    float s, c; sincosf(-TWO_PI_F * (float)i * (1.f/1024.f), &s, &c);
    twg[i] = make_float2(c, s);
  }
}

// ---------------------------------------------------------------------------
// Spatial half (verified R4-R13): 32x32 tile/block, 4 px/thread, one dispatch.
// ---------------------------------------------------------------------------
__global__ __launch_bounds__(256)
void spatial_kernel(const float* __restrict__ pred, const float* __restrict__ targ,
                    const float* __restrict__ mask, double* __restrict__ acc){
  __shared__ float sp[36*37];
  __shared__ float st[36*37];
  __shared__ float smkf[38*39];
  __shared__ unsigned long long mrow[38];
  __shared__ float pmg[34*35];
  __shared__ float tmg[34*35];
  __shared__ float sc[4];

  const int tid = threadIdx.x;
  const int x0 = blockIdx.x << 5, y0 = blockIdx.y << 5;
  const int z = blockIdx.z;
  const size_t ib = (size_t)z * ((size_t)HW * HW);

  for (int i = tid; i < 1296; i += 256){
    int a = i / 36, b = i % 36;
    int gy = y0 - 2 + a, gx = x0 - 2 + b;
    float pv = 0.f, tv = 0.f;
    if ((unsigned)gy < HW && (unsigned)gx < HW){
      size_t idx = ib + (size_t)gy * HW + gx;
      pv = pred[idx]; tv = targ[idx];
    }
    sp[a*37+b] = pv; st[a*37+b] = tv;
  }
  for (int i = tid; i < 1444; i += 256){
    int a = i / 38, b = i % 38;
    int gy = y0 - 3 + a, gx = x0 - 3 + b;
    float v = 0.f;
    if ((unsigned)gy < HW && (unsigned)gx < HW) v = mask[ib + (size_t)gy * HW + gx];
    smkf[a*39+b] = v;
  }
  __syncthreads();

  if (tid < 38){
    unsigned long long w = 0ull;
    #pragma unroll
    for (int x = 0; x < 38; x++)
      w |= (smkf[tid*39 + x] > 0.5f) ? (1ull << x) : 0ull;
    mrow[tid] = w;
  }

  for (int i = tid; i < 1156; i += 256){
    int iy = i / 34, ix = i % 34;
    int gy = y0 - 1 + iy, gx = x0 - 1 + ix;
    float pv = 0.f, tv = 0.f;
    if ((unsigned)gy < HW && (unsigned)gx < HW){
      int o = (iy)*37 + ix;
      float a00=sp[o], a01=sp[o+1], a02=sp[o+2];
      float a10=sp[o+37],           a12=sp[o+39];
      float a20=sp[o+74], a21=sp[o+75], a22=sp[o+76];
      float gxp = (a02 + 2.f*a12 + a22) - (a00 + 2.f*a10 + a20);
      float gyp = (a20 + 2.f*a21 + a22) - (a00 + 2.f*a01 + a02);
      pv = fsqrt(gxp*gxp + gyp*gyp + 1e-8f);
      float b00=st[o], b01=st[o+1], b02=st[o+2];
      float b10=st[o+37],           b12=st[o+39];
      float b20=st[o+74], b21=st[o+75], b22=st[o+76];
      float gxt = (b02 + 2.f*b12 + b22) - (b00 + 2.f*b10 + b20);
      float gyt = (b20 + 2.f*b21 + b22) - (b00 + 2.f*b01 + b02);
      tv = fsqrt(gxt*gxt + gyt*gyt + 1e-8f);
    }
    pmg[iy*35+ix] = pv; tmg[iy*35+ix] = tv;
  }
  __syncthreads();

  const int ty = tid >> 5, tx = tid & 31;
  const int r0 = ty << 2;

  int c1[10], c2[10], c3[10];
  #pragma unroll
  for (int j = 0; j < 10; j++){
    unsigned w = (unsigned)(mrow[r0 + j] >> tx);
    c3[j] = __popc(w & 0x7Fu);
    c2[j] = __popc((w >> 1) & 0x1Fu);
    c1[j] = __popc((w >> 2) & 0x7u);
  }

  float P[3][3], Q[3][3], A[3][3], B[3][3];
  #pragma unroll
  for (int rr = 0; rr < 3; rr++)
    #pragma unroll
    for (int cc = 0; cc < 3; cc++){
      P[rr][cc] = sp[(r0+1+rr)*37 + tx+1+cc];
      Q[rr][cc] = st[(r0+1+rr)*37 + tx+1+cc];
      A[rr][cc] = pmg[(r0+rr)*35 + tx+cc];
      B[rr][cc] = tmg[(r0+rr)*35 + tx+cc];
    }

  float accg = 0.f, accs = 0.f, accl = 0.f;
  #pragma unroll
  for (int k = 0; k < 4; k++){
    if (k){
      #pragma unroll
      for (int cc = 0; cc < 3; cc++){
        P[0][cc]=P[1][cc]; P[1][cc]=P[2][cc]; P[2][cc]=sp[(r0+k+3)*37 + tx+1+cc];
        Q[0][cc]=Q[1][cc]; Q[1][cc]=Q[2][cc]; Q[2][cc]=st[(r0+k+3)*37 + tx+1+cc];
        A[0][cc]=A[1][cc]; A[1][cc]=A[2][cc]; A[2][cc]=pmg[(r0+k+2)*35 + tx+cc];
        B[0][cc]=B[1][cc]; B[1][cc]=B[2][cc]; B[2][cc]=tmg[(r0+k+2)*35 + tx+cc];
      }
    }
    float gxp = (P[0][2]+2.f*P[1][2]+P[2][2]) - (P[0][0]+2.f*P[1][0]+P[2][0]);
    float gyp = (P[2][0]+2.f*P[2][1]+P[2][2]) - (P[0][0]+2.f*P[0][1]+P[0][2]);
    float cvp = 4.f*P[1][1] - P[0][1] - P[1][0] - P[1][2] - P[2][1];
    float gxt = (Q[0][2]+2.f*Q[1][2]+Q[2][2]) - (Q[0][0]+2.f*Q[1][0]+Q[2][0]);
    float gyt = (Q[2][0]+2.f*Q[2][1]+Q[2][2]) - (Q[0][0]+2.f*Q[0][1]+Q[0][2]);
    float cvt = 4.f*Q[1][1] - Q[0][1] - Q[1][0] - Q[1][2] - Q[2][1];

    float sd = fabsf(A[1][1] - B[1][1]);
    float x1 = gxp + 1e-8f, y1 = gyp;
    float x2 = gxt + 1e-8f, y2 = gyt;
    float dd = fabsf(fast_atan2f(y1*x2 - x1*y2, x1*x2 + y1*y2));
    float cd = fabsf(cvp - cvt);

    int s1 = c1[k+2]+c1[k+3]+c1[k+4];
    int s2 = c2[k+1]+c2[k+2]+c2[k+3]+c2[k+4]+c2[k+5];
    int s3 = c3[k]+c3[k+1]+c3[k+2]+c3[k+3]+c3[k+4]+c3[k+5]+c3[k+6];
    float w1 = (s1 > 0 && s1 <  9) ? 1.f : 0.f;
    float w2 = (s2 > 0 && s2 < 25) ? 1.f : 0.f;
    float w3 = (s3 > 0 && s3 < 49) ? 1.f : 0.f;

    accg += (sd + dd) * (w1 + 0.5f*(w2 + w3)) + cd * (2.f*w1 + w2 + w3);

    float s9 = 0.f, s9q = 0.f;
    #pragma unroll
    for (int rr = 0; rr < 3; rr++)
      #pragma unroll
      for (int cc = 0; cc < 3; cc++){ s9 += P[rr][cc]; s9q += P[rr][cc]*P[rr][cc]; }
    float lm = s9 * (1.f/9.f), lq = s9q * (1.f/9.f);
    accs += fsqrt(fmaxf(lq - lm*lm, 1e-8f)) * w1;

    float psx = (A[0][2]+2.f*A[1][2]+A[2][2]) - (A[0][0]+2.f*A[1][0]+A[2][0]);
    float psy = (A[2][0]+2.f*A[2][1]+A[2][2]) - (A[0][0]+2.f*A[0][1]+A[0][2]);
    float pch = fsqrt(psx*psx + psy*psy + 1e-8f);
    float tsx = (B[0][2]+2.f*B[1][2]+B[2][2]) - (B[0][0]+2.f*B[1][0]+B[2][0]);
    float tsy = (B[2][0]+2.f*B[2][1]+B[2][2]) - (B[0][0]+2.f*B[0][1]+B[0][2]);
    float tch = fsqrt(tsx*tsx + tsy*tsy + 1e-8f);
    accl += fabsf(pch - tch) * w1;
  }

  float g  = block_reduce_add_f(accg, sc);
  float sm = block_reduce_add_f(accs, sc);
  float sl = block_reduce_add_f(accl, sc);
  if (tid == 0){
    int slot = (blockIdx.x + blockIdx.y * 7 + z * 13) & (NSLOT - 1);
    atomicAdd(&acc[0*NSLOT + slot], (double)g);
    atomicAdd(&acc[1*NSLOT + slot], (double)sm);
    atomicAdd(&acc[2*NSLOT + slot], (double)sl);
  }
}

// ---------------------------------------------------------------------------
// Lane-xor exchange (HW-verified R13): DPP for h=1,2,8; ds_swizzle h=4,16;
// bpermute h=32.
// ---------------------------------------------------------------------------
__device__ __forceinline__ float lane_xor(float x, int h, int lane){
  int xi = __float_as_int(x);
  int r;
  if (h == 1)       r = __builtin_amdgcn_update_dpp(xi, xi, 0xB1, 0xF, 0xF, true);
  else if (h == 2)  r = __builtin_amdgcn_update_dpp(xi, xi, 0x4E, 0xF, 0xF, true);
  else if (h == 8)  r = __builtin_amdgcn_update_dpp(xi, xi, 0x128, 0xF, 0xF, true);
  else if (h == 4)  r = __builtin_amdgcn_ds_swizzle(xi, 0x101F);  // xor4
  else if (h == 16) r = __builtin_amdgcn_ds_swizzle(xi, 0x401F);  // xor16
  else              r = __builtin_amdgcn_ds_bpermute((lane ^ 32) << 2, xi);
  return __int_as_float(r);
}

// ---------------------------------------------------------------------------
// Wave-level 1024-pt FFT (verified R6-R13): 64 (cross-lane) x 16 (in-register).
// Input: lane q, slot j holds x[j + 16*brev6(q)]. Output: slot j = X[q + 64*j].
// ---------------------------------------------------------------------------
#define FC 0.70710678118654752f
#define FC1 0.92387953251128676f
#define FS1 0.38268343236508977f

__device__ __forceinline__ void bfly(float2& a, float2& b){
  float tx = b.x, ty = b.y;
  b.x = a.x - tx; b.y = a.y - ty;
  a.x += tx;      a.y += ty;
}
__device__ __forceinline__ void cmul_c(float2& b, float wr, float wi){
  float tx = wr*b.x - wi*b.y, ty = wr*b.y + wi*b.x;
  b.x = tx; b.y = ty;
}
__device__ __forceinline__ void rotmi(float2& b){   // b *= -i
  float t = b.x; b.x = b.y; b.y = -t;
}

__device__ __forceinline__ void fft16_reg(float2* v){
  float2 y[16];
  y[0]=v[0];  y[1]=v[8];  y[2]=v[4];  y[3]=v[12];
  y[4]=v[2];  y[5]=v[10]; y[6]=v[6];  y[7]=v[14];
  y[8]=v[1];  y[9]=v[9];  y[10]=v[5]; y[11]=v[13];
  y[12]=v[3]; y[13]=v[11];y[14]=v[7]; y[15]=v[15];
  #pragma unroll
  for (int g = 0; g < 8; g++) bfly(y[2*g], y[2*g+1]);
  #pragma unroll
  for (int g = 0; g < 4; g++){
    int b = 4*g;
    bfly(y[b], y[b+2]);
    rotmi(y[b+3]); bfly(y[b+1], y[b+3]);
  }
  #pragma unroll
  for (int g = 0; g < 2; g++){
    int b = 8*g;
    bfly(y[b], y[b+4]);
    cmul_c(y[b+5],  FC, -FC); bfly(y[b+1], y[b+5]);
    rotmi(y[b+6]);            bfly(y[b+2], y[b+6]);
    cmul_c(y[b+7], -FC, -FC); bfly(y[b+3], y[b+7]);
  }
  bfly(y[0], y[8]);
  cmul_c(y[9],   FC1, -FS1); bfly(y[1], y[9]);
  cmul_c(y[10],  FC,  -FC);  bfly(y[2], y[10]);
  cmul_c(y[11],  FS1, -FC1); bfly(y[3], y[11]);
  rotmi(y[12]);              bfly(y[4], y[12]);
  cmul_c(y[13], -FS1, -FC1); bfly(y[5], y[13]);
  cmul_c(y[14], -FC,  -FC);  bfly(y[6], y[14]);
  cmul_c(y[15], -FC1, -FS1); bfly(y[7], y[15]);
  #pragma unroll
  for (int j = 0; j < 16; j++) v[j] = y[j];
}

__device__ __forceinline__ void fft1024_wave(float2* v, int lane,
                                             const float2* __restrict__ twg){
  #pragma unroll
  for (int s = 0; s < 6; s++){
    const int h = 1 << s;
    const bool up = (lane & h) != 0;
    float2 w = make_float2(1.f, 0.f);
    if (s > 0) w = twg[(lane & (h - 1)) << (9 - s)];
    #pragma unroll
    for (int j = 0; j < 16; j++){
      float ox = lane_xor(v[j].x, h, lane);
      float oy = lane_xor(v[j].y, h, lane);
      float cx = up ? v[j].x : ox;
      float cy = up ? v[j].y : oy;
      float tx, ty;
      if (s == 0){ tx = cx; ty = cy; }
      else { tx = w.x*cx - w.y*cy; ty = w.x*cy + w.y*cx; }
      v[j].x = up ? (ox - tx) : (v[j].x + tx);
      v[j].y = up ? (oy - ty) : (v[j].y + ty);
    }
  }
  float2 wq = twg[lane];
  float2 cur = make_float2(1.f, 0.f);
  #pragma unroll
  for (int j = 1; j < 16; j++){
    cur = cmulf(cur, wq);
    v[j] = cmulf(v[j], cur);
  }
  fft16_reg(v);
}

// ---------------------------------------------------------------------------
// FFT pass 1 + tiled transpose: Zt layout [y>>3][k][y&7] (fp32 float2).
// Store phase is fully coalesced: per (jb,jj) the 512 threads write 4 KB of
// CONTIGUOUS addresses (addr = bx*8192 + k*8 + yl, yl fastest with tid).
// This removes the ~1M scattered 32/64-B segments of the flat [k][y] layout.
// ---------------------------------------------------------------------------
__global__ __launch_bounds__(512)
void fft_rows_t_kernel(const float* __restrict__ pred, const float* __restrict__ targ,
                       float2* __restrict__ Zt, const float2* __restrict__ twg){
  __shared__ float2 tile[4][64][9];
  const int tid = threadIdx.x;
  const int lane = tid & 63;
  const int w = tid >> 6;
  const int y0 = blockIdx.x << 3;
  const size_t ibase = ((size_t)blockIdx.y * HW + (y0 + w)) * HW;
  const int rb = __brev(lane) >> 26;
  const float4* p4 = (const float4*)(pred + ibase);
  const float4* t4 = (const float4*)(targ + ibase);
  float2 v[16];
  #pragma unroll
  for (int m = 0; m < 4; m++){
    float4 a = p4[4*rb + m];
    float4 b = t4[4*rb + m];
    v[4*m+0] = make_float2(a.x, b.x);
    v[4*m+1] = make_float2(a.y, b.y);
    v[4*m+2] = make_float2(a.z, b.z);
    v[4*m+3] = make_float2(a.w, b.w);
  }
  fft1024_wave(v, lane, twg);
  float2* zb = Zt + (size_t)blockIdx.y * HW * HW + (size_t)blockIdx.x * 8192;
  const int yl = tid & 7, kl = tid >> 3;
  #pragma unroll
  for (int jb = 0; jb < 4; jb++){
    __syncthreads();
    #pragma unroll
    for (int jj = 0; jj < 4; jj++) tile[jj][lane][w] = v[4*jb + jj];
    __syncthreads();
    #pragma unroll
    for (int jj = 0; jj < 4; jj++){
      int k = ((jb << 2) + jj) * 64 + kl;
      zb[k * 8 + yl] = tile[jj][kl][yl];     // contiguous across the block
    }
  }
}

// ---------------------------------------------------------------------------
// FFT pass 2 + reduce (R10/R13-proven structure): one FFT per wave, Hermitian
// partner via natural-order LDS. Reads the tiled Zt: lane's 16-y chunk =
// two 64-B fully-utilized contiguous segments (4 float4 each).
// ---------------------------------------------------------------------------
__device__ __forceinline__ void freq_contrib(float2 Zk, float2 Zm, int k1, int k2,
                                             float& ms, float& ps){
  int di = k1 - 512, dj = k2 - 512;
  if (di*di + dj*dj < 94372) return;         // dist > 307.2  <=>  r2 >= 94372
  float pr = 0.5f*(Zk.x + Zm.x);
  float pi = 0.5f*(Zk.y - Zm.y);
  float tr = 0.5f*(Zk.y + Zm.y);
  float ti = 0.5f*(Zm.x - Zk.x);
  float p2 = pr*pr + pi*pi;
  float t2 = tr*tr + ti*ti;
  ms += p2 + t2 - 2.f*fsqrt(p2*t2);
  float re = pr*tr + pi*ti;
  float im = pi*tr - pr*ti;
  float pd = fast_atan2f(im, re);
  ps += pd*pd;
}

__global__ __launch_bounds__(256)
void fft_cols2_kernel(const float2* __restrict__ Z, const float2* __restrict__ twg,
                      double* __restrict__ acc){
  __shared__ float2 ex[4][1024];            // per-wave natural-order spectrum
  const int lane = threadIdx.x & 63;
  const int w = threadIdx.x >> 6;           // 0..3
  const int p = 2 * blockIdx.x + (w >> 1);  // pair index, 0..512 valid
  const bool valid = (p <= 512);
  const int r = (w & 1) ? ((1024 - p) & 1023) : p;   // this wave's Zt row (k)
  const float2* base = Z + (size_t)blockIdx.y * HW * HW;
  const int rb = __brev(lane) >> 26;

  float2 v[16];
  if (valid){
    const float4* f4 = (const float4*)base;
    #pragma unroll
    for (int s = 0; s < 2; s++){
      size_t o = (size_t)(2*rb + s) * 4096 + (size_t)r * 4;  // float4 units
      #pragma unroll
      for (int q = 0; q < 4; q++){
        float4 x = f4[o + q];
        v[8*s + 2*q]     = make_float2(x.x, x.y);
        v[8*s + 2*q + 1] = make_float2(x.z, x.w);
      }
    }
    fft1024_wave(v, lane, twg);
    #pragma unroll
    for (int j = 0; j < 16; j++) ex[w][lane + (j << 6)] = v[j];
  }
  __syncthreads();
  if (!valid) return;
  const bool self = (p == 0) || (p == 512);
  if ((w & 1) && self) return;              // duplicate row: LDS written, no contribs

  const float2* pb = ex[w ^ 1];             // partner spectrum, natural order
  float ms = 0.f, ps = 0.f;
  #pragma unroll
  for (int j = 0; j < 16; j++){
    int k = lane + (j << 6);
    float2 zm = pb[(1024 - k) & 1023];      // Z_partner(-k)
    freq_contrib(v[j], zm, k, r, ms, ps);
  }
  #pragma unroll
  for (int o = 32; o > 0; o >>= 1){
    ms += __shfl_down(ms, o, 64);
    ps += __shfl_down(ps, o, 64);
  }
  if (lane == 0){
    int slot = (r + blockIdx.y * 11) & (NSLOT - 1);
    atomicAdd(&acc[3*NSLOT + slot], (double)ms);
    atomicAdd(&acc[4*NSLOT + slot], (double)ps);
  }
}

// ---------------------------------------------------------------------------
__global__ void finalize_kernel(const double* __restrict__ acc, float* __restrict__ out){
  const int t = threadIdx.x;   // 64 threads
  double v[5];
  #pragma unroll
  for (int s = 0; s < 5; s++) v[s] = acc[s*NSLOT + t];
  #pragma unroll
  for (int o = 32; o > 0; o >>= 1)
    #pragma unroll
    for (int s = 0; s < 5; s++) v[s] += __shfl_down(v[s], o, 64);
  if (t == 0){
    const double inv = 1.0 / 8388608.0;      // mean over 8*1024*1024
    double grad   = v[0] * inv / 3.0;        // / len(bms)
    double smooth = v[1] * inv;
    double slope  = v[2] * inv;
    double freq   = (v[3] + 2.0 * v[4]) * inv;
    double total  = 2.0*grad + 1.5*freq + 3.0*smooth + 2.0*slope;
    out[0] = (float)total;
    out[1] = (float)grad;
    out[2] = (float)freq;
    out[3] = (float)smooth;
    out[4] = (float)slope;
  }
}

extern "C" void kernel_launch(void* const* d_in, const int* in_sizes, int n_in,
                              void* d_out, int out_size, void* d_ws, size_t ws_size,
                              hipStream_t stream){
  const float* pred = (const float*)d_in[0];
  const float* targ = (const float*)d_in[1];
  const float* mask = (const float*)d_in[2];
  double* acc  = (double*)d_ws;                         // [0, 2560)
  float2* twg  = (float2*)((char*)d_ws + 4096);         // [4096, 8192)
  float2* Z    = (float2*)((char*)d_ws + 8192);         // 8 x 8 MiB fp32 images
  // ws_size ~256 MiB (measured R9) — 64 MiB Z fits with margin.

  setup_kernel<<<2, 256, 0, stream>>>(acc, twg);
  spatial_kernel<<<dim3(32, 32, 8), 256, 0, stream>>>(pred, targ, mask, acc);
  fft_rows_t_kernel<<<dim3(128, 8), 512, 0, stream>>>(pred, targ, Z, twg);
  fft_cols2_kernel<<<dim3(257, 8), 256, 0, stream>>>(Z, twg, acc);
  finalize_kernel<<<1, 64, 0, stream>>>(acc, (float*)d_out);
}